// Round 1
// baseline (3264.935 us; speedup 1.0000x reference)
//
#include <hip/hip_runtime.h>

#define E_EDGES 800000
#define NN 50000
#define C 128
#define EAC 70
#define EF 65
#define SCALE 0.08838834764831845f  /* 128^-0.5 */

typedef __attribute__((ext_vector_type(8))) short short8;
typedef __attribute__((ext_vector_type(4))) float floatx4;

__device__ __forceinline__ unsigned short f2bf(float f) {
  unsigned u = __builtin_bit_cast(unsigned, f);
  unsigned r = (u + 0x7FFFu + ((u >> 16) & 1u)) >> 16;
  return (unsigned short)r;
}
__device__ __forceinline__ float bf2f(unsigned short h) {
  unsigned u = ((unsigned)h) << 16;
  return __builtin_bit_cast(float, u);
}

// ---------------- precompute: folded weights in B-frag layout (bf16) --------
// layout: elem(arr)[((s*8+t)*64 + l)*8 + j] = W[s*32 + (l>>4)*8 + j][t*16 + (l&15)]
// arrays: 0 WF1=Wf[0:128]+Wf[256:384], 1 WF2=Wf[128:256]-Wf[256:384],
//         2 WQ, 3 WK, 4 WF4=Wf[384:449] zero-padded to K=96
__global__ void prep_kernel(const float* __restrict__ Wf, const float* __restrict__ Wq,
                            const float* __restrict__ Wk, unsigned short* __restrict__ wfrag) {
  int idx = blockIdx.x * 256 + threadIdx.x;
  if (idx >= 4 * 16384 + 12288) return;
  int arr = idx >> 14;
  int rem = idx & 16383;
  int j = rem & 7;
  int l = (rem >> 3) & 63;
  int st = rem >> 9;
  int s = st >> 3, t = st & 7;
  int k = s * 32 + (l >> 4) * 8 + j;
  int n = t * 16 + (l & 15);
  float v;
  if (arr == 0)      v = Wf[k * C + n] + Wf[(256 + k) * C + n];
  else if (arr == 1) v = Wf[(128 + k) * C + n] - Wf[(256 + k) * C + n];
  else if (arr == 2) v = Wq[k * C + n];
  else if (arr == 3) v = Wk[k * C + n];
  else               v = (k < EF) ? Wf[(384 + k) * C + n] : 0.f;
  wfrag[idx] = f2bf(v);
}

// ---------------- edge kernel: 32 edges per wave ----------------------------
__global__ __launch_bounds__(256) void edge_kernel(
    const float* __restrict__ x, const int* __restrict__ ei,
    const float* __restrict__ ea, const float* __restrict__ bfv,
    const float* __restrict__ Wa, const unsigned short* __restrict__ wfrag,
    float* __restrict__ P, float* __restrict__ a_sum) {
  __shared__ unsigned short f_lds[4][32][136];  // per-wave 32x128 bf16, +8 pad
  const int l = threadIdx.x & 63;
  const int w = threadIdx.x >> 6;
  const int lo = l & 15, quad = l >> 4;
  const int e0 = (blockIdx.x * 4 + w) * 32;
  const int* src = ei;
  const int* tgt = ei + E_EDGES;

  const short8* WF1 = (const short8*)(wfrag);
  const short8* WF2 = (const short8*)(wfrag + 16384);
  const short8* WQ  = (const short8*)(wfrag + 32768);
  const short8* WK  = (const short8*)(wfrag + 49152);
  const short8* WF4 = (const short8*)(wfrag + 65536);

  // ---- gather A-fragments (A[m=lane&15][k=quad*8+j]) ----
  short8 niF[2][4], njF[2][4], eaF[2][3];
  float maskv[2][4];
  int srcRow[2][4];
  for (int mt = 0; mt < 2; ++mt) {
    int e = e0 + 16 * mt + lo;
    int rs = src[e], rt = tgt[e];
    const float* xr = x + (size_t)rs * C;
    const float* yr = x + (size_t)rt * C;
    for (int s = 0; s < 4; ++s) {
      int kb = s * 32 + quad * 8;
      short8 a, b;
      for (int j = 0; j < 8; ++j) a[j] = (short)f2bf(xr[kb + j]);
      for (int j = 0; j < 8; ++j) b[j] = (short)f2bf(yr[kb + j]);
      niF[mt][s] = a;
      njF[mt][s] = b;
    }
    const float* er = ea + (size_t)e * EAC;
    for (int s = 0; s < 3; ++s) {
      short8 a;
      for (int j = 0; j < 8; ++j) {
        int k = s * 32 + quad * 8 + j;
        a[j] = (short)(k < EF ? f2bf(er[k]) : (unsigned short)0);
      }
      eaF[mt][s] = a;
    }
    for (int i = 0; i < 4; ++i) {
      int e2 = e0 + 16 * mt + quad * 4 + i;
      srcRow[mt][i] = src[e2];
      maskv[mt][i] = (ea[(size_t)e2 * EAC] < 8.f) ? 1.f : 0.f;
    }
  }

  // ---- f = elu(ni@WF1 + nj@WF2 + ea@WF4 + bf) * mask ; write bf16 to LDS ----
  for (int t = 0; t < 8; ++t) {
    floatx4 acc[2];
    acc[0] = (floatx4){0.f, 0.f, 0.f, 0.f};
    acc[1] = (floatx4){0.f, 0.f, 0.f, 0.f};
    for (int s = 0; s < 4; ++s) {
      short8 b = WF1[(s * 8 + t) * 64 + l];
      acc[0] = __builtin_amdgcn_mfma_f32_16x16x32_bf16(niF[0][s], b, acc[0], 0, 0, 0);
      acc[1] = __builtin_amdgcn_mfma_f32_16x16x32_bf16(niF[1][s], b, acc[1], 0, 0, 0);
    }
    for (int s = 0; s < 4; ++s) {
      short8 b = WF2[(s * 8 + t) * 64 + l];
      acc[0] = __builtin_amdgcn_mfma_f32_16x16x32_bf16(njF[0][s], b, acc[0], 0, 0, 0);
      acc[1] = __builtin_amdgcn_mfma_f32_16x16x32_bf16(njF[1][s], b, acc[1], 0, 0, 0);
    }
    for (int s = 0; s < 3; ++s) {
      short8 b = WF4[(s * 8 + t) * 64 + l];
      acc[0] = __builtin_amdgcn_mfma_f32_16x16x32_bf16(eaF[0][s], b, acc[0], 0, 0, 0);
      acc[1] = __builtin_amdgcn_mfma_f32_16x16x32_bf16(eaF[1][s], b, acc[1], 0, 0, 0);
    }
    float bias = bfv[lo + 16 * t];
    for (int mt = 0; mt < 2; ++mt)
      for (int i = 0; i < 4; ++i) {
        float v = acc[mt][i] + bias;      // C/D: row=quad*4+i, col=lo+16t
        v = v > 0.f ? v : expm1f(v);
        v *= maskv[mt][i];
        f_lds[w][16 * mt + quad * 4 + i][lo + 16 * t] = f2bf(v);
      }
  }
  __syncthreads();

  // ---- f A-frags from LDS ----
  short8 fF[2][4];
  for (int mt = 0; mt < 2; ++mt) {
    const short8* frow = (const short8*)&f_lds[w][16 * mt + lo][0];
    for (int s = 0; s < 4; ++s) fF[mt][s] = frow[s * 4 + quad];
  }

  // ---- q = ni@Wq, k = f@Wk, partial a = sum_c q*k*Wa[c]*scale ----
  floatx4 pa[2];
  pa[0] = (floatx4){0.f, 0.f, 0.f, 0.f};
  pa[1] = (floatx4){0.f, 0.f, 0.f, 0.f};
  for (int t = 0; t < 8; ++t) {
    floatx4 qa0 = (floatx4){0.f, 0.f, 0.f, 0.f}, qa1 = qa0, ka0 = qa0, ka1 = qa0;
    for (int s = 0; s < 4; ++s) {
      short8 b = WQ[(s * 8 + t) * 64 + l];
      qa0 = __builtin_amdgcn_mfma_f32_16x16x32_bf16(niF[0][s], b, qa0, 0, 0, 0);
      qa1 = __builtin_amdgcn_mfma_f32_16x16x32_bf16(niF[1][s], b, qa1, 0, 0, 0);
    }
    for (int s = 0; s < 4; ++s) {
      short8 b = WK[(s * 8 + t) * 64 + l];
      ka0 = __builtin_amdgcn_mfma_f32_16x16x32_bf16(fF[0][s], b, ka0, 0, 0, 0);
      ka1 = __builtin_amdgcn_mfma_f32_16x16x32_bf16(fF[1][s], b, ka1, 0, 0, 0);
    }
    float wa = Wa[lo + 16 * t];
    pa[0] += qa0 * ka0 * wa;
    pa[1] += qa1 * ka1 * wa;
  }
  // reduce over the 16 lanes of each quad (cols); all lanes end with row sums
  for (int mt = 0; mt < 2; ++mt)
    for (int i = 0; i < 4; ++i) {
      float v = pa[mt][i];
      v += __shfl_xor(v, 1);
      v += __shfl_xor(v, 2);
      v += __shfl_xor(v, 4);
      v += __shfl_xor(v, 8);
      pa[mt][i] = v;
    }

  // ---- a, a_sum atomics, z = exp(a)*f scatter into P ----
  float coeff[2][4];
  for (int mt = 0; mt < 2; ++mt)
    for (int i = 0; i < 4; ++i) {
      float a = tanhf(pa[mt][i] * SCALE);
      coeff[mt][i] = expf(a);
      if (lo == 0) atomicAdd(a_sum + srcRow[mt][i], a);
    }
  for (int mt = 0; mt < 2; ++mt)
    for (int i = 0; i < 4; ++i) {
      float cf = coeff[mt][i];
      float* Prow = P + (size_t)srcRow[mt][i] * C;
      const short8 fv8 = *(const short8*)&f_lds[w][16 * mt + quad * 4 + i][lo * 8];
      for (int j = 0; j < 8; ++j)
        atomicAdd(Prow + lo * 8 + j, cf * bf2f((unsigned short)fv8[j]));
    }
}

// ---------------- node kernel: out = (x + exp(-a_sum)*P) @ Wu + bu ----------
__global__ __launch_bounds__(256) void node_kernel(
    const float* __restrict__ x, const float* __restrict__ P,
    const float* __restrict__ a_sum, const float* __restrict__ Wu,
    const float* __restrict__ bu, float* __restrict__ out) {
  __shared__ float rows[32][129];
  int b0 = blockIdx.x * 32;
  for (int idx = threadIdx.x; idx < 32 * 128; idx += 256) {
    int r = idx >> 7, i = idx & 127;
    int n = b0 + r;
    float v = 0.f;
    if (n < NN) v = x[(size_t)n * C + i] + expf(-a_sum[n]) * P[(size_t)n * C + i];
    rows[r][i] = v;
  }
  __syncthreads();
  int tr = threadIdx.x >> 4;  // rows tr*2, tr*2+1
  int tc = threadIdx.x & 15;  // cols tc*8 .. +8
  floatx4 a00 = (floatx4){0.f, 0.f, 0.f, 0.f}, a01 = a00, a10 = a00, a11 = a00;
  for (int i = 0; i < C; ++i) {
    float r0 = rows[tr * 2][i], r1 = rows[tr * 2 + 1][i];
    const floatx4* wr = (const floatx4*)(Wu + (size_t)i * C + tc * 8);
    floatx4 w0 = wr[0], w1 = wr[1];
    a00 += w0 * r0; a01 += w1 * r0;
    a10 += w0 * r1; a11 += w1 * r1;
  }
  const floatx4* bv = (const floatx4*)(bu + tc * 8);
  floatx4 bb0 = bv[0], bb1 = bv[1];
  int n0 = b0 + tr * 2;
  if (n0 < NN) {
    floatx4* o = (floatx4*)(out + (size_t)n0 * C + tc * 8);
    o[0] = a00 + bb0; o[1] = a01 + bb1;
  }
  if (n0 + 1 < NN) {
    floatx4* o = (floatx4*)(out + (size_t)(n0 + 1) * C + tc * 8);
    o[0] = a10 + bb0; o[1] = a11 + bb1;
  }
}

extern "C" void kernel_launch(void* const* d_in, const int* in_sizes, int n_in,
                              void* d_out, int out_size, void* d_ws, size_t ws_size,
                              hipStream_t stream) {
  const float* x  = (const float*)d_in[0];
  const int*   ei = (const int*)d_in[1];
  const float* ea = (const float*)d_in[2];
  const float* Wf = (const float*)d_in[3];
  const float* bf = (const float*)d_in[4];
  const float* Wq = (const float*)d_in[5];
  const float* Wk = (const float*)d_in[6];
  const float* Wa = (const float*)d_in[7];
  const float* Wu = (const float*)d_in[8];
  const float* bu = (const float*)d_in[9];
  float* out = (float*)d_out;

  // workspace layout
  float* P      = (float*)d_ws;                              // 25,600,000 B
  float* a_sum  = (float*)((char*)d_ws + 25600000);          //    200,000 B
  unsigned short* wfrag = (unsigned short*)((char*)d_ws + 25800000);  // 155,648 B

  hipMemsetAsync(d_ws, 0, 25800000, stream);
  prep_kernel<<<304, 256, 0, stream>>>(Wf, Wq, Wk, wfrag);
  edge_kernel<<<6250, 256, 0, stream>>>(x, ei, ea, bf, Wa, wfrag, P, a_sum);
  node_kernel<<<(NN + 31) / 32, 256, 0, stream>>>(x, P, a_sum, Wu, bu, out);
}

// Round 2
// 1477.847 us; speedup vs baseline: 2.2093x; 2.2093x over previous
//
#include <hip/hip_runtime.h>

#define E_EDGES 800000
#define NN 50000
#define C 128
#define EAC 70
#define EF 65
#define SCALE 0.08838834764831845f  /* 128^-0.5 */

typedef __attribute__((ext_vector_type(8))) short short8;
typedef __attribute__((ext_vector_type(4))) float floatx4;

__device__ __forceinline__ unsigned short f2bf(float f) {
  unsigned u = __builtin_bit_cast(unsigned, f);
  unsigned r = (u + 0x7FFFu + ((u >> 16) & 1u)) >> 16;
  return (unsigned short)r;
}
__device__ __forceinline__ float bf2f(unsigned short h) {
  unsigned u = ((unsigned)h) << 16;
  return __builtin_bit_cast(float, u);
}

// ---------------- precompute: folded weights in B-frag layout (bf16) --------
// layout: elem(arr)[((s*8+t)*64 + l)*8 + j] = W[s*32 + (l>>4)*8 + j][t*16 + (l&15)]
// arrays: 0 WF1=Wf[0:128]+Wf[256:384], 1 WF2=Wf[128:256]-Wf[256:384],
//         2 WQ, 3 WK, 4 WF4=Wf[384:449] zero-padded to K=96
__global__ void prep_kernel(const float* __restrict__ Wf, const float* __restrict__ Wq,
                            const float* __restrict__ Wk, unsigned short* __restrict__ wfrag) {
  int idx = blockIdx.x * 256 + threadIdx.x;
  if (idx >= 4 * 16384 + 12288) return;
  int arr = idx >> 14;
  int rem = idx & 16383;
  int j = rem & 7;
  int l = (rem >> 3) & 63;
  int st = rem >> 9;
  int s = st >> 3, t = st & 7;
  int k = s * 32 + (l >> 4) * 8 + j;
  int n = t * 16 + (l & 15);
  float v;
  if (arr == 0)      v = Wf[k * C + n] + Wf[(256 + k) * C + n];
  else if (arr == 1) v = Wf[(128 + k) * C + n] - Wf[(256 + k) * C + n];
  else if (arr == 2) v = Wq[k * C + n];
  else if (arr == 3) v = Wk[k * C + n];
  else               v = (k < EF) ? Wf[(384 + k) * C + n] : 0.f;
  wfrag[idx] = f2bf(v);
}

// ---------------- CSR build ----------------
__global__ void hist_kernel(const int* __restrict__ src, int* __restrict__ deg) {
  int e = blockIdx.x * 256 + threadIdx.x;
  if (e < E_EDGES) atomicAdd(deg + src[e], 1);
}

// single-block exclusive scan of deg -> offs
__global__ __launch_bounds__(1024) void scan_kernel(const int* __restrict__ deg,
                                                    int* __restrict__ offs) {
  __shared__ int buf[1024];
  __shared__ int carry_s;
  int t = threadIdx.x;
  if (t == 0) carry_s = 0;
  __syncthreads();
  for (int base = 0; base < NN; base += 1024) {
    int v = (base + t < NN) ? deg[base + t] : 0;
    buf[t] = v;
    __syncthreads();
    for (int d = 1; d < 1024; d <<= 1) {
      int add = (t >= d) ? buf[t - d] : 0;
      __syncthreads();
      buf[t] += add;
      __syncthreads();
    }
    int incl = buf[t];
    int carry = carry_s;
    if (base + t < NN) offs[base + t] = carry + incl - v;
    __syncthreads();
    if (t == 1023) carry_s = carry + incl;
    __syncthreads();
  }
}

__global__ void pos_kernel(const int* __restrict__ src, const int* __restrict__ offs,
                           int* __restrict__ cursor, int* __restrict__ perm) {
  int e = blockIdx.x * 256 + threadIdx.x;
  if (e < E_EDGES) {
    int r = src[e];
    int p = offs[r] + atomicAdd(cursor + r, 1);
    perm[p] = e;
  }
}

// ---------------- edge kernel: 32 edges per wave ----------------------------
template <bool CSR>
__global__ __launch_bounds__(256) void edge_kernel(
    const float* __restrict__ x, const int* __restrict__ ei,
    const float* __restrict__ ea, const float* __restrict__ bfv,
    const float* __restrict__ Wa, const unsigned short* __restrict__ wfrag,
    float* __restrict__ P, float* __restrict__ a_sum,
    unsigned short* __restrict__ Z, float* __restrict__ A) {
  __shared__ unsigned short f_lds[4][32][136];  // per-wave 32x128 bf16, +8 pad
  const int l = threadIdx.x & 63;
  const int w = threadIdx.x >> 6;
  const int lo = l & 15, quad = l >> 4;
  const int e0 = (blockIdx.x * 4 + w) * 32;
  const int* src = ei;
  const int* tgt = ei + E_EDGES;

  const short8* WF1 = (const short8*)(wfrag);
  const short8* WF2 = (const short8*)(wfrag + 16384);
  const short8* WQ  = (const short8*)(wfrag + 32768);
  const short8* WK  = (const short8*)(wfrag + 49152);
  const short8* WF4 = (const short8*)(wfrag + 65536);

  // ---- gather A-fragments (A[m=lane&15][k=quad*8+j]) ----
  short8 niF[2][4], njF[2][4], eaF[2][3];
  float maskv[2][4];
  int srcRow[2][4];
  for (int mt = 0; mt < 2; ++mt) {
    int e = e0 + 16 * mt + lo;
    int rs = src[e], rt = tgt[e];
    const float* xr = x + (size_t)rs * C;
    const float* yr = x + (size_t)rt * C;
    for (int s = 0; s < 4; ++s) {
      int kb = s * 32 + quad * 8;
      const floatx4* xv = (const floatx4*)(xr + kb);
      const floatx4* yv = (const floatx4*)(yr + kb);
      floatx4 x0 = xv[0], x1 = xv[1], y0 = yv[0], y1 = yv[1];
      short8 a, b;
      for (int j = 0; j < 4; ++j) { a[j] = (short)f2bf(x0[j]); a[4 + j] = (short)f2bf(x1[j]); }
      for (int j = 0; j < 4; ++j) { b[j] = (short)f2bf(y0[j]); b[4 + j] = (short)f2bf(y1[j]); }
      niF[mt][s] = a;
      njF[mt][s] = b;
    }
    const float* er = ea + (size_t)e * EAC;
    for (int s = 0; s < 3; ++s) {
      short8 a;
      for (int j = 0; j < 8; ++j) {
        int k = s * 32 + quad * 8 + j;
        a[j] = (short)(k < EF ? f2bf(er[k]) : (unsigned short)0);
      }
      eaF[mt][s] = a;
    }
    for (int i = 0; i < 4; ++i) {
      int e2 = e0 + 16 * mt + quad * 4 + i;
      srcRow[mt][i] = src[e2];
      maskv[mt][i] = (ea[(size_t)e2 * EAC] < 8.f) ? 1.f : 0.f;
    }
  }

  // ---- f = elu(ni@WF1 + nj@WF2 + ea@WF4 + bf) * mask ; write bf16 to LDS ----
  for (int t = 0; t < 8; ++t) {
    floatx4 acc[2];
    acc[0] = (floatx4){0.f, 0.f, 0.f, 0.f};
    acc[1] = (floatx4){0.f, 0.f, 0.f, 0.f};
    for (int s = 0; s < 4; ++s) {
      short8 b = WF1[(s * 8 + t) * 64 + l];
      acc[0] = __builtin_amdgcn_mfma_f32_16x16x32_bf16(niF[0][s], b, acc[0], 0, 0, 0);
      acc[1] = __builtin_amdgcn_mfma_f32_16x16x32_bf16(niF[1][s], b, acc[1], 0, 0, 0);
    }
    for (int s = 0; s < 4; ++s) {
      short8 b = WF2[(s * 8 + t) * 64 + l];
      acc[0] = __builtin_amdgcn_mfma_f32_16x16x32_bf16(njF[0][s], b, acc[0], 0, 0, 0);
      acc[1] = __builtin_amdgcn_mfma_f32_16x16x32_bf16(njF[1][s], b, acc[1], 0, 0, 0);
    }
    for (int s = 0; s < 3; ++s) {
      short8 b = WF4[(s * 8 + t) * 64 + l];
      acc[0] = __builtin_amdgcn_mfma_f32_16x16x32_bf16(eaF[0][s], b, acc[0], 0, 0, 0);
      acc[1] = __builtin_amdgcn_mfma_f32_16x16x32_bf16(eaF[1][s], b, acc[1], 0, 0, 0);
    }
    float bias = bfv[lo + 16 * t];
    for (int mt = 0; mt < 2; ++mt)
      for (int i = 0; i < 4; ++i) {
        float v = acc[mt][i] + bias;      // C/D: row=quad*4+i, col=lo+16t
        v = v > 0.f ? v : expm1f(v);
        v *= maskv[mt][i];
        f_lds[w][16 * mt + quad * 4 + i][lo + 16 * t] = f2bf(v);
      }
  }
  __syncthreads();

  // ---- f A-frags from LDS ----
  short8 fF[2][4];
  for (int mt = 0; mt < 2; ++mt) {
    const short8* frow = (const short8*)&f_lds[w][16 * mt + lo][0];
    for (int s = 0; s < 4; ++s) fF[mt][s] = frow[s * 4 + quad];
  }

  // ---- q = ni@Wq, k = f@Wk, partial a = sum_c q*k*Wa[c]*scale ----
  floatx4 pa[2];
  pa[0] = (floatx4){0.f, 0.f, 0.f, 0.f};
  pa[1] = (floatx4){0.f, 0.f, 0.f, 0.f};
  for (int t = 0; t < 8; ++t) {
    floatx4 qa0 = (floatx4){0.f, 0.f, 0.f, 0.f}, qa1 = qa0, ka0 = qa0, ka1 = qa0;
    for (int s = 0; s < 4; ++s) {
      short8 b = WQ[(s * 8 + t) * 64 + l];
      qa0 = __builtin_amdgcn_mfma_f32_16x16x32_bf16(niF[0][s], b, qa0, 0, 0, 0);
      qa1 = __builtin_amdgcn_mfma_f32_16x16x32_bf16(niF[1][s], b, qa1, 0, 0, 0);
    }
    for (int s = 0; s < 4; ++s) {
      short8 b = WK[(s * 8 + t) * 64 + l];
      ka0 = __builtin_amdgcn_mfma_f32_16x16x32_bf16(fF[0][s], b, ka0, 0, 0, 0);
      ka1 = __builtin_amdgcn_mfma_f32_16x16x32_bf16(fF[1][s], b, ka1, 0, 0, 0);
    }
    float wa = Wa[lo + 16 * t];
    pa[0] += qa0 * ka0 * wa;
    pa[1] += qa1 * ka1 * wa;
  }
  for (int mt = 0; mt < 2; ++mt)
    for (int i = 0; i < 4; ++i) {
      float v = pa[mt][i];
      v += __shfl_xor(v, 1);
      v += __shfl_xor(v, 2);
      v += __shfl_xor(v, 4);
      v += __shfl_xor(v, 8);
      pa[mt][i] = v;
    }

  // ---- a, coeff = exp(a) ----
  float coeff[2][4], aval[2][4];
  for (int mt = 0; mt < 2; ++mt)
    for (int i = 0; i < 4; ++i) {
      float a = tanhf(pa[mt][i] * SCALE);
      aval[mt][i] = a;
      coeff[mt][i] = expf(a);
      if (!CSR && lo == 0) atomicAdd(a_sum + srcRow[mt][i], a);
    }

  if (CSR) {
    // write a[e] and z[e] = exp(a)*f (bf16) coalesced, no atomics
    for (int mt = 0; mt < 2; ++mt)
      for (int i = 0; i < 4; ++i) {
        int e2 = e0 + 16 * mt + quad * 4 + i;
        float cf = coeff[mt][i];
        const short8 fv8 = *(const short8*)&f_lds[w][16 * mt + quad * 4 + i][lo * 8];
        short8 zv;
        for (int j = 0; j < 8; ++j) zv[j] = (short)f2bf(cf * bf2f((unsigned short)fv8[j]));
        *(short8*)(Z + (size_t)e2 * C + lo * 8) = zv;
        if (lo == 0) A[e2] = aval[mt][i];
      }
  } else {
    for (int mt = 0; mt < 2; ++mt)
      for (int i = 0; i < 4; ++i) {
        float cf = coeff[mt][i];
        float* Prow = P + (size_t)srcRow[mt][i] * C;
        const short8 fv8 = *(const short8*)&f_lds[w][16 * mt + quad * 4 + i][lo * 8];
        for (int j = 0; j < 8; ++j)
          atomicAdd(Prow + lo * 8 + j, cf * bf2f((unsigned short)fv8[j]));
      }
  }
}

// ---------------- CSR gather + update GEMM ----------------------------------
__global__ __launch_bounds__(256) void gather_node_kernel(
    const float* __restrict__ x, const unsigned short* __restrict__ Z,
    const float* __restrict__ A, const int* __restrict__ offs,
    const int* __restrict__ deg, const int* __restrict__ perm,
    const float* __restrict__ Wu, const float* __restrict__ bu,
    float* __restrict__ out) {
  __shared__ float rows[32][129];
  int b0 = blockIdx.x * 32;
  int w = threadIdx.x >> 6, l = threadIdx.x & 63;
  for (int r = w; r < 32; r += 4) {
    int n = b0 + r;
    float ax = 0.f, ay = 0.f, asum = 0.f;
    if (n < NN) {
      int beg = offs[n], dn = deg[n];
      for (int j = 0; j < dn; ++j) {
        int e = perm[beg + j];
        asum += A[e];
        const ushort2 zz = *(const ushort2*)(Z + (size_t)e * C + l * 2);
        ax += bf2f(zz.x);
        ay += bf2f(zz.y);
      }
      float cf = expf(-asum);
      rows[r][l * 2]     = x[(size_t)n * C + l * 2]     + cf * ax;
      rows[r][l * 2 + 1] = x[(size_t)n * C + l * 2 + 1] + cf * ay;
    } else {
      rows[r][l * 2] = 0.f;
      rows[r][l * 2 + 1] = 0.f;
    }
  }
  __syncthreads();
  int tr = threadIdx.x >> 4;
  int tc = threadIdx.x & 15;
  floatx4 a00 = (floatx4){0.f, 0.f, 0.f, 0.f}, a01 = a00, a10 = a00, a11 = a00;
  for (int i = 0; i < C; ++i) {
    float r0 = rows[tr * 2][i], r1 = rows[tr * 2 + 1][i];
    const floatx4* wr = (const floatx4*)(Wu + (size_t)i * C + tc * 8);
    floatx4 w0 = wr[0], w1 = wr[1];
    a00 += w0 * r0; a01 += w1 * r0;
    a10 += w0 * r1; a11 += w1 * r1;
  }
  const floatx4* bv = (const floatx4*)(bu + tc * 8);
  floatx4 bb0 = bv[0], bb1 = bv[1];
  int n0 = b0 + tr * 2;
  if (n0 < NN) {
    floatx4* o = (floatx4*)(out + (size_t)n0 * C + tc * 8);
    o[0] = a00 + bb0; o[1] = a01 + bb1;
  }
  if (n0 + 1 < NN) {
    floatx4* o = (floatx4*)(out + (size_t)(n0 + 1) * C + tc * 8);
    o[0] = a10 + bb0; o[1] = a11 + bb1;
  }
}

// ---------------- fallback node kernel (atomic path) ------------------------
__global__ __launch_bounds__(256) void node_kernel(
    const float* __restrict__ x, const float* __restrict__ P,
    const float* __restrict__ a_sum, const float* __restrict__ Wu,
    const float* __restrict__ bu, float* __restrict__ out) {
  __shared__ float rows[32][129];
  int b0 = blockIdx.x * 32;
  for (int idx = threadIdx.x; idx < 32 * 128; idx += 256) {
    int r = idx >> 7, i = idx & 127;
    int n = b0 + r;
    float v = 0.f;
    if (n < NN) v = x[(size_t)n * C + i] + expf(-a_sum[n]) * P[(size_t)n * C + i];
    rows[r][i] = v;
  }
  __syncthreads();
  int tr = threadIdx.x >> 4;
  int tc = threadIdx.x & 15;
  floatx4 a00 = (floatx4){0.f, 0.f, 0.f, 0.f}, a01 = a00, a10 = a00, a11 = a00;
  for (int i = 0; i < C; ++i) {
    float r0 = rows[tr * 2][i], r1 = rows[tr * 2 + 1][i];
    const floatx4* wr = (const floatx4*)(Wu + (size_t)i * C + tc * 8);
    floatx4 w0 = wr[0], w1 = wr[1];
    a00 += w0 * r0; a01 += w1 * r0;
    a10 += w0 * r1; a11 += w1 * r1;
  }
  const floatx4* bv = (const floatx4*)(bu + tc * 8);
  floatx4 bb0 = bv[0], bb1 = bv[1];
  int n0 = b0 + tr * 2;
  if (n0 < NN) {
    floatx4* o = (floatx4*)(out + (size_t)n0 * C + tc * 8);
    o[0] = a00 + bb0; o[1] = a01 + bb1;
  }
  if (n0 + 1 < NN) {
    floatx4* o = (floatx4*)(out + (size_t)(n0 + 1) * C + tc * 8);
    o[0] = a10 + bb0; o[1] = a11 + bb1;
  }
}

extern "C" void kernel_launch(void* const* d_in, const int* in_sizes, int n_in,
                              void* d_out, int out_size, void* d_ws, size_t ws_size,
                              hipStream_t stream) {
  const float* x  = (const float*)d_in[0];
  const int*   ei = (const int*)d_in[1];
  const float* ea = (const float*)d_in[2];
  const float* Wf = (const float*)d_in[3];
  const float* bf = (const float*)d_in[4];
  const float* Wq = (const float*)d_in[5];
  const float* Wk = (const float*)d_in[6];
  const float* Wa = (const float*)d_in[7];
  const float* Wu = (const float*)d_in[8];
  const float* bu = (const float*)d_in[9];
  float* out = (float*)d_out;

  const int* src = ei;

  // CSR-path workspace layout
  size_t off = 0;
  auto take = [&](size_t n) { size_t r = off; off += (n + 255) & ~(size_t)255; return r; };
  size_t oZ    = take((size_t)E_EDGES * C * 2);       // 204.8 MB bf16 z
  size_t oA    = take((size_t)E_EDGES * 4);           // 3.2 MB a
  size_t oDeg  = take((size_t)NN * 4);
  size_t oOffs = take((size_t)NN * 4);
  size_t oCur  = take((size_t)NN * 4);
  size_t oPerm = take((size_t)E_EDGES * 4);
  size_t oWf   = take((size_t)(4 * 16384 + 12288) * 2);
  size_t need = off;

  if (ws_size >= need) {
    unsigned short* Z = (unsigned short*)((char*)d_ws + oZ);
    float* A          = (float*)((char*)d_ws + oA);
    int* deg          = (int*)((char*)d_ws + oDeg);
    int* offs         = (int*)((char*)d_ws + oOffs);
    int* cursor       = (int*)((char*)d_ws + oCur);
    int* perm         = (int*)((char*)d_ws + oPerm);
    unsigned short* wfrag = (unsigned short*)((char*)d_ws + oWf);

    hipMemsetAsync(deg, 0, NN * 4, stream);
    hipMemsetAsync(cursor, 0, NN * 4, stream);
    prep_kernel<<<304, 256, 0, stream>>>(Wf, Wq, Wk, wfrag);
    hist_kernel<<<(E_EDGES + 255) / 256, 256, 0, stream>>>(src, deg);
    scan_kernel<<<1, 1024, 0, stream>>>(deg, offs);
    pos_kernel<<<(E_EDGES + 255) / 256, 256, 0, stream>>>(src, offs, cursor, perm);
    edge_kernel<true><<<6250, 256, 0, stream>>>(x, ei, ea, bf, Wa, wfrag,
                                                nullptr, nullptr, Z, A);
    gather_node_kernel<<<(NN + 31) / 32, 256, 0, stream>>>(x, Z, A, offs, deg, perm,
                                                           Wu, bu, out);
  } else {
    // fallback: atomic-scatter path (R1)
    float* P      = (float*)d_ws;
    float* a_sum  = (float*)((char*)d_ws + 25600000);
    unsigned short* wfrag = (unsigned short*)((char*)d_ws + 25800000);
    hipMemsetAsync(d_ws, 0, 25800000, stream);
    prep_kernel<<<304, 256, 0, stream>>>(Wf, Wq, Wk, wfrag);
    edge_kernel<false><<<6250, 256, 0, stream>>>(x, ei, ea, bf, Wa, wfrag,
                                                 P, a_sum, nullptr, nullptr);
    node_kernel<<<(NN + 31) / 32, 256, 0, stream>>>(x, P, a_sum, Wu, bu, out);
  }
}

// Round 3
// 1149.123 us; speedup vs baseline: 2.8412x; 1.2861x over previous
//
#include <hip/hip_runtime.h>

#define E_EDGES 800000
#define NN 50000
#define C 128
#define EAC 70
#define EF 65
#define SCALE 0.08838834764831845f  /* 128^-0.5 */

typedef __attribute__((ext_vector_type(8))) short short8;
typedef __attribute__((ext_vector_type(4))) float floatx4;
typedef __attribute__((ext_vector_type(4))) short short4v;

__device__ __forceinline__ unsigned short f2bf(float f) {
  unsigned u = __builtin_bit_cast(unsigned, f);
  unsigned r = (u + 0x7FFFu + ((u >> 16) & 1u)) >> 16;
  return (unsigned short)r;
}
__device__ __forceinline__ float bf2f(unsigned short h) {
  unsigned u = ((unsigned)h) << 16;
  return __builtin_bit_cast(float, u);
}

// ---------------- prep: folded f-weights in B-frag layout (bf16) ------------
// elem(arr)[((s*8+t)*64+l)*8+j] = W[s*32+(l>>4)*8+j][t*16+(l&15)]
// arr0 WF1=Wf[0:128]+Wf[256:384], arr1 WF2=Wf[128:256]-Wf[256:384],
// arr2 WF4=Wf[384:449] zero-padded to K=96 (12288 elems)
__global__ void prep_kernel(const float* __restrict__ Wf, unsigned short* __restrict__ wfrag) {
  int idx = blockIdx.x * 256 + threadIdx.x;
  if (idx >= 45056) return;
  int arr = idx >> 14;
  int rem = idx & 16383;
  int j = rem & 7;
  int l = (rem >> 3) & 63;
  int st = rem >> 9;
  int s = st >> 3, t = st & 7;
  int k = s * 32 + (l >> 4) * 8 + j;
  int n = t * 16 + (l & 15);
  float v;
  if (arr == 0)      v = Wf[k * C + n] + Wf[(256 + k) * C + n];
  else if (arr == 1) v = Wf[(128 + k) * C + n] - Wf[(256 + k) * C + n];
  else               v = (k < EF) ? Wf[(384 + k) * C + n] : 0.f;
  wfrag[idx] = f2bf(v);
}

// Wm[b][d] = scale * sum_c Wq[b][c] * Wa[c] * Wk[d][c]
__global__ void wm_kernel(const float* __restrict__ Wq, const float* __restrict__ Wk,
                          const float* __restrict__ Wa, float* __restrict__ Wm) {
  int idx = blockIdx.x * 256 + threadIdx.x;
  if (idx >= C * C) return;
  int b = idx >> 7, d = idx & 127;
  const float* wq = Wq + (size_t)b * C;
  const float* wk = Wk + (size_t)d * C;
  float s = 0.f;
  for (int c = 0; c < C; ++c) s += wq[c] * Wa[c] * wk[c];
  Wm[idx] = s * SCALE;
}

// XB = bf16(x)
__global__ void xcvt_kernel(const float* __restrict__ x, unsigned short* __restrict__ XB) {
  int idx = blockIdx.x * 256 + threadIdx.x;
  if (idx >= NN * (C / 4)) return;
  floatx4 v = ((const floatx4*)x)[idx];
  short4v o;
  for (int j = 0; j < 4; ++j) o[j] = (short)f2bf(v[j]);
  ((short4v*)XB)[idx] = o;
}

// M = bf16(x @ Wm)   (node-GEMM, 32 rows/block)
__global__ __launch_bounds__(256) void m_kernel(const float* __restrict__ x,
                                                const float* __restrict__ Wm,
                                                unsigned short* __restrict__ M) {
  __shared__ float rows[32][129];
  int b0 = blockIdx.x * 32;
  for (int idx = threadIdx.x; idx < 32 * 128; idx += 256) {
    int r = idx >> 7, i = idx & 127;
    int n = b0 + r;
    rows[r][i] = (n < NN) ? x[(size_t)n * C + i] : 0.f;
  }
  __syncthreads();
  int tr = threadIdx.x >> 4;
  int tc = threadIdx.x & 15;
  floatx4 a00 = (floatx4){0,0,0,0}, a01 = a00, a10 = a00, a11 = a00;
  for (int i = 0; i < C; ++i) {
    float r0 = rows[tr * 2][i], r1 = rows[tr * 2 + 1][i];
    const floatx4* wr = (const floatx4*)(Wm + (size_t)i * C + tc * 8);
    floatx4 w0 = wr[0], w1 = wr[1];
    a00 += w0 * r0; a01 += w1 * r0;
    a10 += w0 * r1; a11 += w1 * r1;
  }
  int n0 = b0 + tr * 2;
  for (int rr = 0; rr < 2; ++rr) {
    int n = n0 + rr;
    if (n < NN) {
      floatx4 v0 = rr ? a10 : a00, v1 = rr ? a11 : a01;
      short8 o;
      for (int j = 0; j < 4; ++j) { o[j] = (short)f2bf(v0[j]); o[4 + j] = (short)f2bf(v1[j]); }
      *(short8*)(M + (size_t)n * C + tc * 8) = o;
    }
  }
}

// ---------------- CSR build ----------------
__global__ void hist_kernel(const int* __restrict__ src, int* __restrict__ deg) {
  int e = blockIdx.x * 256 + threadIdx.x;
  if (e < E_EDGES) atomicAdd(deg + src[e], 1);
}

__global__ __launch_bounds__(1024) void scan_kernel(const int* __restrict__ deg,
                                                    int* __restrict__ offs) {
  __shared__ int buf[1024];
  const int CH = 49;  // 1024*49 >= 50000
  int t = threadIdx.x, base = t * CH;
  int s = 0;
  for (int k = 0; k < CH; ++k)
    if (base + k < NN) s += deg[base + k];
  buf[t] = s;
  __syncthreads();
  for (int d = 1; d < 1024; d <<= 1) {
    int add = (t >= d) ? buf[t - d] : 0;
    __syncthreads();
    buf[t] += add;
    __syncthreads();
  }
  int excl = buf[t] - s;
  for (int k = 0; k < CH; ++k)
    if (base + k < NN) { offs[base + k] = excl; excl += deg[base + k]; }
}

__global__ void pos_kernel(const int* __restrict__ src, const int* __restrict__ tgt,
                           const int* __restrict__ offs, int* __restrict__ cursor,
                           int* __restrict__ perm, int* __restrict__ srcs,
                           int* __restrict__ tgts) {
  int e = blockIdx.x * 256 + threadIdx.x;
  if (e < E_EDGES) {
    int r = src[e];
    int p = offs[r] + atomicAdd(cursor + r, 1);
    perm[p] = e;
    if (srcs) { srcs[p] = r; tgts[p] = tgt[e]; }
  }
}

// EAB[p][0..71] = bf16(ea[perm[p]][c]) for c<65 else 0 ; MK[p] = mask
__global__ void eacvt_kernel(const float* __restrict__ ea, const int* __restrict__ perm,
                             unsigned short* __restrict__ EAB, float* __restrict__ MK) {
  int gid = blockIdx.x * 256 + threadIdx.x;
  if (gid >= E_EDGES * 9) return;
  int p = gid / 9;
  int ch = gid - p * 9;
  int e = perm[p];
  int c0 = ch * 8;
  const float* er = ea + (size_t)e * EAC;
  short8 o;
  for (int j = 0; j < 8; ++j) {
    int c = c0 + j;
    o[j] = (short)((c < EF) ? f2bf(er[c]) : (unsigned short)0);
  }
  *(short8*)(EAB + (size_t)p * 72 + c0) = o;
  if (ch == 0) MK[p] = (er[0] < 8.f) ? 1.f : 0.f;
}

// ---------------- edge kernel: 16 edges per wave ----------------------------
// MODE 0: full (XB/EAB/MK/srcs/tgts, CSR Z)   MODE 1: mid (fp32 gathers via perm, CSR Z)
// MODE 2: no-CSR fallback (atomic P scatter)
template <int MODE>
__global__ __launch_bounds__(256, 4) void edge_kernel(
    const float* __restrict__ x, const unsigned short* __restrict__ XB,
    const int* __restrict__ src, const int* __restrict__ tgt,
    const float* __restrict__ ea, const float* __restrict__ bfv,
    const unsigned short* __restrict__ wfrag, const unsigned short* __restrict__ EAB,
    const float* __restrict__ MK, const int* __restrict__ perm,
    const int* __restrict__ srcs, const int* __restrict__ tgts,
    const unsigned short* __restrict__ M, float* __restrict__ a_sum,
    unsigned short* __restrict__ Z, float* __restrict__ P) {
  __shared__ unsigned short f_lds[4][16][136];
  const int l = threadIdx.x & 63;
  const int w = threadIdx.x >> 6;
  const int lo = l & 15, quad = l >> 4;
  const int e0 = (blockIdx.x * 4 + w) * 16;

  const short8* WF1 = (const short8*)wfrag;
  const short8* WF2 = (const short8*)(wfrag + 16384);
  const short8* WF4 = (const short8*)(wfrag + 32768);

  // ---- A-fragment rows (m = lo) ----
  int p = e0 + lo;
  int s_row, t_row, e_log;
  if (MODE == 0)      { s_row = srcs[p]; t_row = tgts[p]; e_log = 0; }
  else if (MODE == 1) { e_log = perm[p]; s_row = src[e_log]; t_row = tgt[e_log]; }
  else                { e_log = p; s_row = src[p]; t_row = tgt[p]; }

  short8 niF[4], njF[4], eaF[3];
  if (MODE == 0) {
    const short8* xr = (const short8*)(XB + (size_t)s_row * C);
    const short8* yr = (const short8*)(XB + (size_t)t_row * C);
    for (int s = 0; s < 4; ++s) { niF[s] = xr[s * 4 + quad]; njF[s] = yr[s * 4 + quad]; }
    const short8* er8 = (const short8*)(EAB + (size_t)p * 72);
    eaF[0] = er8[quad];
    eaF[1] = er8[4 + quad];
    if (quad == 0) eaF[2] = er8[8];
    else { short8 z0; for (int j = 0; j < 8; ++j) z0[j] = 0; eaF[2] = z0; }
  } else {
    const float* xr = x + (size_t)s_row * C;
    const float* yr = x + (size_t)t_row * C;
    for (int s = 0; s < 4; ++s) {
      int kb = s * 32 + quad * 8;
      const floatx4* xv = (const floatx4*)(xr + kb);
      const floatx4* yv = (const floatx4*)(yr + kb);
      floatx4 x0 = xv[0], x1 = xv[1], y0 = yv[0], y1 = yv[1];
      short8 a, b;
      for (int j = 0; j < 4; ++j) { a[j] = (short)f2bf(x0[j]); a[4 + j] = (short)f2bf(x1[j]); }
      for (int j = 0; j < 4; ++j) { b[j] = (short)f2bf(y0[j]); b[4 + j] = (short)f2bf(y1[j]); }
      niF[s] = a; njF[s] = b;
    }
    const float* er = ea + (size_t)e_log * EAC;
    for (int s = 0; s < 3; ++s) {
      short8 a;
      for (int j = 0; j < 8; ++j) {
        int k = s * 32 + quad * 8 + j;
        a[j] = (short)(k < EF ? f2bf(er[k]) : (unsigned short)0);
      }
      eaF[s] = a;
    }
  }

  // ---- C-layout rows (row = quad*4+i) ----
  float maskv[4];
  int srcRow[4];
  const unsigned short* mrow[4];
  for (int i = 0; i < 4; ++i) {
    int pc = e0 + quad * 4 + i;
    int sr; float mk;
    if (MODE == 0)      { sr = srcs[pc]; mk = MK[pc]; }
    else if (MODE == 1) { int el = perm[pc]; sr = src[el]; mk = (ea[(size_t)el * EAC] < 8.f) ? 1.f : 0.f; }
    else                { sr = src[pc]; mk = (ea[(size_t)pc * EAC] < 8.f) ? 1.f : 0.f; }
    srcRow[i] = sr; maskv[i] = mk;
    mrow[i] = M + (size_t)sr * C;
  }

  // ---- f = elu(ni@WF1 + nj@WF2 + ea@WF4 + bf)*mask ; pa_i += f . m[src] ----
  floatx4 pa = (floatx4){0.f, 0.f, 0.f, 0.f};
  for (int t = 0; t < 8; ++t) {
    floatx4 acc = (floatx4){0.f, 0.f, 0.f, 0.f};
    for (int s = 0; s < 4; ++s)
      acc = __builtin_amdgcn_mfma_f32_16x16x32_bf16(niF[s], WF1[(s * 8 + t) * 64 + l], acc, 0, 0, 0);
    for (int s = 0; s < 4; ++s)
      acc = __builtin_amdgcn_mfma_f32_16x16x32_bf16(njF[s], WF2[(s * 8 + t) * 64 + l], acc, 0, 0, 0);
    for (int s = 0; s < 3; ++s)
      acc = __builtin_amdgcn_mfma_f32_16x16x32_bf16(eaF[s], WF4[(s * 8 + t) * 64 + l], acc, 0, 0, 0);
    float bias = bfv[lo + 16 * t];
    for (int i = 0; i < 4; ++i) {
      float v = acc[i] + bias;              // C/D: row=quad*4+i, col=lo+16t
      v = v > 0.f ? v : expm1f(v);
      v *= maskv[i];
      f_lds[w][quad * 4 + i][lo + 16 * t] = f2bf(v);
      pa[i] += v * bf2f(mrow[i][lo + 16 * t]);
    }
  }

  // reduce pa over the 16 lanes holding one row's columns
  for (int i = 0; i < 4; ++i) {
    float v = pa[i];
    v += __shfl_xor(v, 1);
    v += __shfl_xor(v, 2);
    v += __shfl_xor(v, 4);
    v += __shfl_xor(v, 8);
    pa[i] = v;
  }

  float coeff[4];
  for (int i = 0; i < 4; ++i) {
    float a = tanhf(pa[i]);   // Wm already includes the 1/sqrt(C) scale
    coeff[i] = expf(a);
    if (lo == 0) atomicAdd(a_sum + srcRow[i], a);
  }

  if (MODE <= 1) {
    for (int i = 0; i < 4; ++i) {
      const short8 fv = *(const short8*)&f_lds[w][quad * 4 + i][lo * 8];
      short8 zv;
      for (int j = 0; j < 8; ++j) zv[j] = (short)f2bf(coeff[i] * bf2f((unsigned short)fv[j]));
      *(short8*)(Z + (size_t)(e0 + quad * 4 + i) * C + lo * 8) = zv;
    }
  } else {
    for (int i = 0; i < 4; ++i) {
      float* Prow = P + (size_t)srcRow[i] * C;
      const short8 fv = *(const short8*)&f_lds[w][quad * 4 + i][lo * 8];
      for (int j = 0; j < 8; ++j)
        atomicAdd(Prow + lo * 8 + j, coeff[i] * bf2f((unsigned short)fv[j]));
    }
  }
}

// ---------------- CSR gather + update GEMM ----------------------------------
__global__ __launch_bounds__(256) void gather_node_kernel(
    const float* __restrict__ x, const unsigned short* __restrict__ Z,
    const float* __restrict__ a_sum, const int* __restrict__ offs,
    const int* __restrict__ deg, const float* __restrict__ Wu,
    const float* __restrict__ bu, float* __restrict__ out) {
  __shared__ float rows[32][129];
  int b0 = blockIdx.x * 32;
  int w = threadIdx.x >> 6, l = threadIdx.x & 63;
  for (int r = w; r < 32; r += 4) {
    int n = b0 + r;
    if (n < NN) {
      int beg = offs[n], dn = deg[n];
      float ax = 0.f, ay = 0.f;
      const unsigned short* zp = Z + (size_t)beg * C + l * 2;
      int j = 0;
      for (; j + 1 < dn; j += 2) {
        ushort2 z0 = *(const ushort2*)zp;
        ushort2 z1 = *(const ushort2*)(zp + C);
        zp += 2 * C;
        ax += bf2f(z0.x) + bf2f(z1.x);
        ay += bf2f(z0.y) + bf2f(z1.y);
      }
      if (j < dn) {
        ushort2 z0 = *(const ushort2*)zp;
        ax += bf2f(z0.x); ay += bf2f(z0.y);
      }
      float cf = expf(-a_sum[n]);
      rows[r][l * 2]     = x[(size_t)n * C + l * 2]     + cf * ax;
      rows[r][l * 2 + 1] = x[(size_t)n * C + l * 2 + 1] + cf * ay;
    } else {
      rows[r][l * 2] = 0.f;
      rows[r][l * 2 + 1] = 0.f;
    }
  }
  __syncthreads();
  int tr = threadIdx.x >> 4;
  int tc = threadIdx.x & 15;
  floatx4 a00 = (floatx4){0,0,0,0}, a01 = a00, a10 = a00, a11 = a00;
  for (int i = 0; i < C; ++i) {
    float r0 = rows[tr * 2][i], r1 = rows[tr * 2 + 1][i];
    const floatx4* wr = (const floatx4*)(Wu + (size_t)i * C + tc * 8);
    floatx4 w0 = wr[0], w1 = wr[1];
    a00 += w0 * r0; a01 += w1 * r0;
    a10 += w0 * r1; a11 += w1 * r1;
  }
  const floatx4* bv = (const floatx4*)(bu + tc * 8);
  floatx4 bb0 = bv[0], bb1 = bv[1];
  int n0 = b0 + tr * 2;
  if (n0 < NN) {
    floatx4* o = (floatx4*)(out + (size_t)n0 * C + tc * 8);
    o[0] = a00 + bb0; o[1] = a01 + bb1;
  }
  if (n0 + 1 < NN) {
    floatx4* o = (floatx4*)(out + (size_t)(n0 + 1) * C + tc * 8);
    o[0] = a10 + bb0; o[1] = a11 + bb1;
  }
}

// ---------------- fallback node kernel (atomic P path) ----------------------
__global__ __launch_bounds__(256) void node_kernel(
    const float* __restrict__ x, const float* __restrict__ P,
    const float* __restrict__ a_sum, const float* __restrict__ Wu,
    const float* __restrict__ bu, float* __restrict__ out) {
  __shared__ float rows[32][129];
  int b0 = blockIdx.x * 32;
  for (int idx = threadIdx.x; idx < 32 * 128; idx += 256) {
    int r = idx >> 7, i = idx & 127;
    int n = b0 + r;
    float v = 0.f;
    if (n < NN) v = x[(size_t)n * C + i] + expf(-a_sum[n]) * P[(size_t)n * C + i];
    rows[r][i] = v;
  }
  __syncthreads();
  int tr = threadIdx.x >> 4;
  int tc = threadIdx.x & 15;
  floatx4 a00 = (floatx4){0,0,0,0}, a01 = a00, a10 = a00, a11 = a00;
  for (int i = 0; i < C; ++i) {
    float r0 = rows[tr * 2][i], r1 = rows[tr * 2 + 1][i];
    const floatx4* wr = (const floatx4*)(Wu + (size_t)i * C + tc * 8);
    floatx4 w0 = wr[0], w1 = wr[1];
    a00 += w0 * r0; a01 += w1 * r0;
    a10 += w0 * r1; a11 += w1 * r1;
  }
  const floatx4* bv = (const floatx4*)(bu + tc * 8);
  floatx4 bb0 = bv[0], bb1 = bv[1];
  int n0 = b0 + tr * 2;
  if (n0 < NN) {
    floatx4* o = (floatx4*)(out + (size_t)n0 * C + tc * 8);
    o[0] = a00 + bb0; o[1] = a01 + bb1;
  }
  if (n0 + 1 < NN) {
    floatx4* o = (floatx4*)(out + (size_t)(n0 + 1) * C + tc * 8);
    o[0] = a10 + bb0; o[1] = a11 + bb1;
  }
}

extern "C" void kernel_launch(void* const* d_in, const int* in_sizes, int n_in,
                              void* d_out, int out_size, void* d_ws, size_t ws_size,
                              hipStream_t stream) {
  const float* x  = (const float*)d_in[0];
  const int*   ei = (const int*)d_in[1];
  const float* ea = (const float*)d_in[2];
  const float* Wf = (const float*)d_in[3];
  const float* bf = (const float*)d_in[4];
  const float* Wq = (const float*)d_in[5];
  const float* Wk = (const float*)d_in[6];
  const float* Wa = (const float*)d_in[7];
  const float* Wu = (const float*)d_in[8];
  const float* bu = (const float*)d_in[9];
  float* out = (float*)d_out;
  const int* src = ei;
  const int* tgt = ei + E_EDGES;

  // ---- full layout ----
  size_t off = 0;
  auto take = [&](size_t n) { size_t r = off; off += (n + 255) & ~(size_t)255; return r; };
  size_t oZ = take((size_t)E_EDGES * C * 2);
  size_t oAs = take((size_t)NN * 4);
  size_t oDeg = take((size_t)NN * 4);
  size_t oOffs = take((size_t)NN * 4);
  size_t oCur = take((size_t)NN * 4);
  size_t oPerm = take((size_t)E_EDGES * 4);
  size_t oWfr = take((size_t)45056 * 2);
  size_t oWm = take((size_t)C * C * 4);
  size_t oM = take((size_t)NN * C * 2);
  size_t need_mid = off;
  size_t oSrcs = take((size_t)E_EDGES * 4);
  size_t oTgts = take((size_t)E_EDGES * 4);
  size_t oXB = take((size_t)NN * C * 2);
  size_t oEAB = take((size_t)E_EDGES * 72 * 2);
  size_t oMK = take((size_t)E_EDGES * 4);
  size_t need_full = off;

  if (ws_size >= need_mid) {
    unsigned short* Z = (unsigned short*)((char*)d_ws + oZ);
    float* a_sum = (float*)((char*)d_ws + oAs);
    int* deg = (int*)((char*)d_ws + oDeg);
    int* offs = (int*)((char*)d_ws + oOffs);
    int* cursor = (int*)((char*)d_ws + oCur);
    int* perm = (int*)((char*)d_ws + oPerm);
    unsigned short* wfrag = (unsigned short*)((char*)d_ws + oWfr);
    float* Wm = (float*)((char*)d_ws + oWm);
    unsigned short* M = (unsigned short*)((char*)d_ws + oM);
    bool full = (ws_size >= need_full);
    int* srcs = full ? (int*)((char*)d_ws + oSrcs) : nullptr;
    int* tgts = full ? (int*)((char*)d_ws + oTgts) : nullptr;
    unsigned short* XB = full ? (unsigned short*)((char*)d_ws + oXB) : nullptr;
    unsigned short* EAB = full ? (unsigned short*)((char*)d_ws + oEAB) : nullptr;
    float* MK = full ? (float*)((char*)d_ws + oMK) : nullptr;

    hipMemsetAsync(a_sum, 0, NN * 4, stream);
    hipMemsetAsync(deg, 0, NN * 4, stream);
    hipMemsetAsync(cursor, 0, NN * 4, stream);
    prep_kernel<<<176, 256, 0, stream>>>(Wf, wfrag);
    wm_kernel<<<64, 256, 0, stream>>>(Wq, Wk, Wa, Wm);
    m_kernel<<<(NN + 31) / 32, 256, 0, stream>>>(x, Wm, M);
    hist_kernel<<<(E_EDGES + 255) / 256, 256, 0, stream>>>(src, deg);
    scan_kernel<<<1, 1024, 0, stream>>>(deg, offs);
    pos_kernel<<<(E_EDGES + 255) / 256, 256, 0, stream>>>(src, tgt, offs, cursor,
                                                          perm, srcs, tgts);
    if (full) {
      xcvt_kernel<<<(NN * (C / 4) + 255) / 256, 256, 0, stream>>>(x, XB);
      eacvt_kernel<<<(E_EDGES * 9 + 255) / 256, 256, 0, stream>>>(ea, perm, EAB, MK);
      edge_kernel<0><<<E_EDGES / 64, 256, 0, stream>>>(x, XB, src, tgt, ea, bf, wfrag,
                                                       EAB, MK, perm, srcs, tgts, M,
                                                       a_sum, Z, nullptr);
    } else {
      edge_kernel<1><<<E_EDGES / 64, 256, 0, stream>>>(x, nullptr, src, tgt, ea, bf,
                                                       wfrag, nullptr, nullptr, perm,
                                                       nullptr, nullptr, M, a_sum, Z,
                                                       nullptr);
    }
    gather_node_kernel<<<(NN + 31) / 32, 256, 0, stream>>>(x, Z, a_sum, offs, deg,
                                                           Wu, bu, out);
  } else {
    // minimal fallback: atomic P scatter, no CSR
    size_t f = 0;
    auto tk = [&](size_t n) { size_t r = f; f += (n + 255) & ~(size_t)255; return r; };
    size_t fP = tk((size_t)NN * C * 4);
    size_t fAs = tk((size_t)NN * 4);
    size_t fWfr = tk((size_t)45056 * 2);
    size_t fWm = tk((size_t)C * C * 4);
    size_t fM = tk((size_t)NN * C * 2);
    float* P = (float*)((char*)d_ws + fP);
    float* a_sum = (float*)((char*)d_ws + fAs);
    unsigned short* wfrag = (unsigned short*)((char*)d_ws + fWfr);
    float* Wm = (float*)((char*)d_ws + fWm);
    unsigned short* M = (unsigned short*)((char*)d_ws + fM);
    hipMemsetAsync(P, 0, (size_t)NN * C * 4, stream);
    hipMemsetAsync(a_sum, 0, NN * 4, stream);
    prep_kernel<<<176, 256, 0, stream>>>(Wf, wfrag);
    wm_kernel<<<64, 256, 0, stream>>>(Wq, Wk, Wa, Wm);
    m_kernel<<<(NN + 31) / 32, 256, 0, stream>>>(x, Wm, M);
    edge_kernel<2><<<E_EDGES / 64, 256, 0, stream>>>(x, nullptr, src, tgt, ea, bf,
                                                     wfrag, nullptr, nullptr, nullptr,
                                                     nullptr, nullptr, M, a_sum,
                                                     nullptr, P);
    node_kernel<<<(NN + 31) / 32, 256, 0, stream>>>(x, P, a_sum, Wu, bu, out);
  }
}

// Round 4
// 902.590 us; speedup vs baseline: 3.6173x; 1.2731x over previous
//
#include <hip/hip_runtime.h>

#define E_EDGES 800000
#define NN 50000
#define C 128
#define EAC 70
#define EF 65
#define SCALE 0.08838834764831845f  /* 128^-0.5 */

typedef __attribute__((ext_vector_type(8))) short short8;
typedef __attribute__((ext_vector_type(4))) float floatx4;

__device__ __forceinline__ unsigned short f2bf(float f) {
  unsigned u = __builtin_bit_cast(unsigned, f);
  unsigned r = (u + 0x7FFFu + ((u >> 16) & 1u)) >> 16;
  return (unsigned short)r;
}
__device__ __forceinline__ float bf2f(unsigned short h) {
  unsigned u = ((unsigned)h) << 16;
  return __builtin_bit_cast(float, u);
}

// ---------------- fused setup: wm | prep | hist ------------------------------
// blocks [0,64): Wm[b][d] = scale * sum_c Wq[b][c]*Wa[c]*Wk[d][c]
// blocks [64,240): wfrag (folded f-weights, B-frag layout bf16)
// blocks [240,3365): histogram of src
__global__ void setup_kernel(const float* __restrict__ Wf, const float* __restrict__ Wq,
                             const float* __restrict__ Wk, const float* __restrict__ Wa,
                             const int* __restrict__ src, unsigned short* __restrict__ wfrag,
                             float* __restrict__ Wm, int* __restrict__ deg) {
  int b = blockIdx.x;
  if (b < 64) {
    int idx = b * 256 + threadIdx.x;          // 16384 = C*C exactly
    int r = idx >> 7, d = idx & 127;
    const float* wq = Wq + (size_t)r * C;
    const float* wk = Wk + (size_t)d * C;
    float s = 0.f;
    for (int c = 0; c < C; ++c) s += wq[c] * Wa[c] * wk[c];
    Wm[idx] = s * SCALE;
  } else if (b < 240) {
    int idx = (b - 64) * 256 + threadIdx.x;   // 45056 exactly
    int arr = idx >> 14;
    int rem = idx & 16383;
    int j = rem & 7;
    int l = (rem >> 3) & 63;
    int st = rem >> 9;
    int s = st >> 3, t = st & 7;
    int k = s * 32 + (l >> 4) * 8 + j;
    int n = t * 16 + (l & 15);
    float v;
    if (arr == 0)      v = Wf[k * C + n] + Wf[(256 + k) * C + n];
    else if (arr == 1) v = Wf[(128 + k) * C + n] - Wf[(256 + k) * C + n];
    else               v = (k < EF) ? Wf[(384 + k) * C + n] : 0.f;
    wfrag[idx] = f2bf(v);
  } else {
    int e = (b - 240) * 256 + threadIdx.x;    // 800000 exactly
    atomicAdd(deg + src[e], 1);
  }
}

// ---------------- M = bf16(x @ Wm) and XB = bf16(x) --------------------------
__global__ __launch_bounds__(256) void m_kernel(const float* __restrict__ x,
                                                const float* __restrict__ Wm,
                                                unsigned short* __restrict__ M,
                                                unsigned short* __restrict__ XB) {
  __shared__ float rows[32][129];
  int b0 = blockIdx.x * 32;
  for (int idx = threadIdx.x; idx < 32 * 128; idx += 256) {
    int r = idx >> 7, i = idx & 127;
    int n = b0 + r;
    float v = 0.f;
    if (n < NN) {
      v = x[(size_t)n * C + i];
      XB[(size_t)n * C + i] = f2bf(v);
    }
    rows[r][i] = v;
  }
  __syncthreads();
  int tr = threadIdx.x >> 4;
  int tc = threadIdx.x & 15;
  floatx4 a00 = (floatx4){0,0,0,0}, a01 = a00, a10 = a00, a11 = a00;
  for (int i = 0; i < C; ++i) {
    float r0 = rows[tr * 2][i], r1 = rows[tr * 2 + 1][i];
    const floatx4* wr = (const floatx4*)(Wm + (size_t)i * C + tc * 8);
    floatx4 w0 = wr[0], w1 = wr[1];
    a00 += w0 * r0; a01 += w1 * r0;
    a10 += w0 * r1; a11 += w1 * r1;
  }
  int n0 = b0 + tr * 2;
  for (int rr = 0; rr < 2; ++rr) {
    int n = n0 + rr;
    if (n < NN) {
      floatx4 v0 = rr ? a10 : a00, v1 = rr ? a11 : a01;
      short8 o;
      for (int j = 0; j < 4; ++j) { o[j] = (short)f2bf(v0[j]); o[4 + j] = (short)f2bf(v1[j]); }
      *(short8*)(M + (size_t)n * C + tc * 8) = o;
    }
  }
}

// ---------------- CSR scan + position scatter --------------------------------
__global__ __launch_bounds__(1024) void scan_kernel(const int* __restrict__ deg,
                                                    int* __restrict__ offs) {
  __shared__ int buf[1024];
  const int CH = 49;
  int t = threadIdx.x, base = t * CH;
  int s = 0;
  for (int k = 0; k < CH; ++k)
    if (base + k < NN) s += deg[base + k];
  buf[t] = s;
  __syncthreads();
  for (int d = 1; d < 1024; d <<= 1) {
    int add = (t >= d) ? buf[t - d] : 0;
    __syncthreads();
    buf[t] += add;
    __syncthreads();
  }
  int excl = buf[t] - s;
  for (int k = 0; k < CH; ++k)
    if (base + k < NN) { offs[base + k] = excl; excl += deg[base + k]; }
}

__global__ void pos_kernel(const int* __restrict__ src, const int* __restrict__ tgt,
                           const int* __restrict__ offs, int* __restrict__ cursor,
                           int* __restrict__ perm, int* __restrict__ srcs,
                           int* __restrict__ tgts) {
  int e = blockIdx.x * 256 + threadIdx.x;   // 800000 exactly
  int r = src[e];
  int p = offs[r] + atomicAdd(cursor + r, 1);
  perm[p] = e;
  srcs[p] = r;
  tgts[p] = tgt[e];
}

// ---------------- edge kernel: 16 edges/wave, CSR order ----------------------
__global__ __launch_bounds__(256, 5) void edge_kernel(
    const unsigned short* __restrict__ XB, const float* __restrict__ ea,
    const float* __restrict__ bfv, const unsigned short* __restrict__ wfrag,
    const int* __restrict__ perm, const int* __restrict__ srcs,
    const int* __restrict__ tgts, const unsigned short* __restrict__ M,
    unsigned short* __restrict__ Z, float* __restrict__ A) {
  __shared__ unsigned short f_lds[4][16][136];
  __shared__ float mask_lds[4][16];
  const int l = threadIdx.x & 63;
  const int w = threadIdx.x >> 6;
  const int lo = l & 15, quad = l >> 4;
  const int e0 = (blockIdx.x * 4 + w) * 16;

  const short8* WF1 = (const short8*)wfrag;
  const short8* WF2 = (const short8*)(wfrag + 16384);
  const short8* WF4 = (const short8*)(wfrag + 32768);

  // A-fragment rows (m = lo): edge at CSR position p
  int p = e0 + lo;
  int sp = srcs[p], tp = tgts[p], ep = perm[p];

  short8 niF[4], njF[4], eaF[3];
  {
    const short8* xr = (const short8*)(XB + (size_t)sp * C);
    const short8* yr = (const short8*)(XB + (size_t)tp * C);
    for (int s = 0; s < 4; ++s) { niF[s] = xr[s * 4 + quad]; njF[s] = yr[s * 4 + quad]; }
  }
  {
    const float* er = ea + (size_t)ep * EAC;     // 280B rows: 8B aligned
    const float2* ca = (const float2*)(er + quad * 8);
    const float2* cb = (const float2*)(er + 32 + quad * 8);
    float2 a0 = ca[0], a1 = ca[1], a2 = ca[2], a3 = ca[3];
    float2 b0 = cb[0], b1 = cb[1], b2 = cb[2], b3 = cb[3];
    short8 t0, t1, t2;
    t0[0] = (short)f2bf(a0.x); t0[1] = (short)f2bf(a0.y);
    t0[2] = (short)f2bf(a1.x); t0[3] = (short)f2bf(a1.y);
    t0[4] = (short)f2bf(a2.x); t0[5] = (short)f2bf(a2.y);
    t0[6] = (short)f2bf(a3.x); t0[7] = (short)f2bf(a3.y);
    t1[0] = (short)f2bf(b0.x); t1[1] = (short)f2bf(b0.y);
    t1[2] = (short)f2bf(b1.x); t1[3] = (short)f2bf(b1.y);
    t1[4] = (short)f2bf(b2.x); t1[5] = (short)f2bf(b2.y);
    t1[6] = (short)f2bf(b3.x); t1[7] = (short)f2bf(b3.y);
    for (int j = 0; j < 8; ++j) t2[j] = 0;
    if (quad == 0) {
      t2[0] = (short)f2bf(er[64]);
      mask_lds[w][lo] = (a0.x < 8.f) ? 1.f : 0.f;
    }
    eaF[0] = t0; eaF[1] = t1; eaF[2] = t2;
  }

  // C-layout metadata (row = quad*4+i at CSR position e0+quad*4+i)
  float maskv[4];
  int srcRow[4];
  for (int i = 0; i < 4; ++i) {
    maskv[i] = mask_lds[w][quad * 4 + i];   // wave-local RAW via in-order DS pipe
    srcRow[i] = srcs[e0 + quad * 4 + i];
  }

  // f = elu(ni@WF1 + nj@WF2 + ea@WF4 + bf) * mask -> LDS (bf16)
  for (int t = 0; t < 8; ++t) {
    floatx4 acc = (floatx4){0.f, 0.f, 0.f, 0.f};
    for (int s = 0; s < 4; ++s)
      acc = __builtin_amdgcn_mfma_f32_16x16x32_bf16(niF[s], WF1[(s * 8 + t) * 64 + l], acc, 0, 0, 0);
    for (int s = 0; s < 4; ++s)
      acc = __builtin_amdgcn_mfma_f32_16x16x32_bf16(njF[s], WF2[(s * 8 + t) * 64 + l], acc, 0, 0, 0);
    for (int s = 0; s < 3; ++s)
      acc = __builtin_amdgcn_mfma_f32_16x16x32_bf16(eaF[s], WF4[(s * 8 + t) * 64 + l], acc, 0, 0, 0);
    float bias = bfv[lo + 16 * t];
    for (int i = 0; i < 4; ++i) {
      float v = acc[i] + bias;            // C/D: row=quad*4+i, col=lo+16t
      v = v > 0.f ? v : expm1f(v);
      v *= maskv[i];
      f_lds[w][quad * 4 + i][lo + 16 * t] = f2bf(v);
    }
  }

  // a = f . M[src]; coeff = exp(tanh(a)); Z = coeff*f; A[p] = a
  for (int i = 0; i < 4; ++i) {
    int pc = e0 + quad * 4 + i;
    const short8 fv = *(const short8*)&f_lds[w][quad * 4 + i][lo * 8];
    const short8 mv = *(const short8*)(M + (size_t)srcRow[i] * C + lo * 8);
    float d = 0.f;
    for (int j = 0; j < 8; ++j)
      d += bf2f((unsigned short)fv[j]) * bf2f((unsigned short)mv[j]);
    d += __shfl_xor(d, 1);
    d += __shfl_xor(d, 2);
    d += __shfl_xor(d, 4);
    d += __shfl_xor(d, 8);
    float a = tanhf(d);                   // Wm includes the 1/sqrt(C) scale
    float cf = expf(a);
    short8 zv;
    for (int j = 0; j < 8; ++j) zv[j] = (short)f2bf(cf * bf2f((unsigned short)fv[j]));
    *(short8*)(Z + (size_t)pc * C + lo * 8) = zv;
    if (lo == 0) A[pc] = a;
  }
}

// ---------------- CSR gather + update GEMM -----------------------------------
__global__ __launch_bounds__(256) void gather_node_kernel(
    const float* __restrict__ x, const unsigned short* __restrict__ Z,
    const float* __restrict__ A, const int* __restrict__ offs,
    const int* __restrict__ deg, const float* __restrict__ Wu,
    const float* __restrict__ bu, float* __restrict__ out) {
  __shared__ float rows[32][129];
  int b0 = blockIdx.x * 32;
  int w = threadIdx.x >> 6, l = threadIdx.x & 63;
  for (int r = w; r < 32; r += 4) {
    int n = b0 + r;
    if (n < NN) {
      int beg = offs[n], dn = deg[n];
      float ax = 0.f, ay = 0.f, asum = 0.f;
      const unsigned short* zp = Z + (size_t)beg * C + l * 2;
      const float* ap = A + beg;
      int j = 0;
      for (; j + 1 < dn; j += 2) {
        ushort2 z0 = *(const ushort2*)zp;
        ushort2 z1 = *(const ushort2*)(zp + C);
        zp += 2 * C;
        asum += ap[j] + ap[j + 1];
        ax += bf2f(z0.x) + bf2f(z1.x);
        ay += bf2f(z0.y) + bf2f(z1.y);
      }
      if (j < dn) {
        ushort2 z0 = *(const ushort2*)zp;
        asum += ap[j];
        ax += bf2f(z0.x); ay += bf2f(z0.y);
      }
      float cf = expf(-asum);
      rows[r][l * 2]     = x[(size_t)n * C + l * 2]     + cf * ax;
      rows[r][l * 2 + 1] = x[(size_t)n * C + l * 2 + 1] + cf * ay;
    } else {
      rows[r][l * 2] = 0.f;
      rows[r][l * 2 + 1] = 0.f;
    }
  }
  __syncthreads();
  int tr = threadIdx.x >> 4;
  int tc = threadIdx.x & 15;
  floatx4 a00 = (floatx4){0,0,0,0}, a01 = a00, a10 = a00, a11 = a00;
  for (int i = 0; i < C; ++i) {
    float r0 = rows[tr * 2][i], r1 = rows[tr * 2 + 1][i];
    const floatx4* wr = (const floatx4*)(Wu + (size_t)i * C + tc * 8);
    floatx4 w0 = wr[0], w1 = wr[1];
    a00 += w0 * r0; a01 += w1 * r0;
    a10 += w0 * r1; a11 += w1 * r1;
  }
  const floatx4* bv = (const floatx4*)(bu + tc * 8);
  floatx4 bb0 = bv[0], bb1 = bv[1];
  int n0 = b0 + tr * 2;
  if (n0 < NN) {
    floatx4* o = (floatx4*)(out + (size_t)n0 * C + tc * 8);
    o[0] = a00 + bb0; o[1] = a01 + bb1;
  }
  if (n0 + 1 < NN) {
    floatx4* o = (floatx4*)(out + (size_t)(n0 + 1) * C + tc * 8);
    o[0] = a10 + bb0; o[1] = a11 + bb1;
  }
}

// ---------------- fallback: natural-order edge kernel with atomic scatter ----
__global__ __launch_bounds__(256, 4) void fb_edge_kernel(
    const float* __restrict__ x, const int* __restrict__ src,
    const int* __restrict__ tgt, const float* __restrict__ ea,
    const float* __restrict__ bfv, const unsigned short* __restrict__ wfrag,
    const unsigned short* __restrict__ M, float* __restrict__ a_sum,
    float* __restrict__ P) {
  __shared__ unsigned short f_lds[4][16][136];
  __shared__ float mask_lds[4][16];
  const int l = threadIdx.x & 63;
  const int w = threadIdx.x >> 6;
  const int lo = l & 15, quad = l >> 4;
  const int e0 = (blockIdx.x * 4 + w) * 16;
  const short8* WF1 = (const short8*)wfrag;
  const short8* WF2 = (const short8*)(wfrag + 16384);
  const short8* WF4 = (const short8*)(wfrag + 32768);

  int p = e0 + lo;
  int sp = src[p], tp = tgt[p];
  short8 niF[4], njF[4], eaF[3];
  {
    const float* xr = x + (size_t)sp * C;
    const float* yr = x + (size_t)tp * C;
    for (int s = 0; s < 4; ++s) {
      int kb = s * 32 + quad * 8;
      const floatx4* xv = (const floatx4*)(xr + kb);
      const floatx4* yv = (const floatx4*)(yr + kb);
      floatx4 x0 = xv[0], x1 = xv[1], y0 = yv[0], y1 = yv[1];
      short8 a, b;
      for (int j = 0; j < 4; ++j) { a[j] = (short)f2bf(x0[j]); a[4 + j] = (short)f2bf(x1[j]); }
      for (int j = 0; j < 4; ++j) { b[j] = (short)f2bf(y0[j]); b[4 + j] = (short)f2bf(y1[j]); }
      niF[s] = a; njF[s] = b;
    }
    const float* er = ea + (size_t)p * EAC;
    const float2* ca = (const float2*)(er + quad * 8);
    const float2* cb = (const float2*)(er + 32 + quad * 8);
    float2 a0 = ca[0], a1 = ca[1], a2 = ca[2], a3 = ca[3];
    float2 b0 = cb[0], b1 = cb[1], b2 = cb[2], b3 = cb[3];
    short8 t0, t1, t2;
    t0[0] = (short)f2bf(a0.x); t0[1] = (short)f2bf(a0.y);
    t0[2] = (short)f2bf(a1.x); t0[3] = (short)f2bf(a1.y);
    t0[4] = (short)f2bf(a2.x); t0[5] = (short)f2bf(a2.y);
    t0[6] = (short)f2bf(a3.x); t0[7] = (short)f2bf(a3.y);
    t1[0] = (short)f2bf(b0.x); t1[1] = (short)f2bf(b0.y);
    t1[2] = (short)f2bf(b1.x); t1[3] = (short)f2bf(b1.y);
    t1[4] = (short)f2bf(b2.x); t1[5] = (short)f2bf(b2.y);
    t1[6] = (short)f2bf(b3.x); t1[7] = (short)f2bf(b3.y);
    for (int j = 0; j < 8; ++j) t2[j] = 0;
    if (quad == 0) {
      t2[0] = (short)f2bf(er[64]);
      mask_lds[w][lo] = (a0.x < 8.f) ? 1.f : 0.f;
    }
    eaF[0] = t0; eaF[1] = t1; eaF[2] = t2;
  }
  float maskv[4];
  int srcRow[4];
  for (int i = 0; i < 4; ++i) {
    maskv[i] = mask_lds[w][quad * 4 + i];
    srcRow[i] = src[e0 + quad * 4 + i];
  }
  for (int t = 0; t < 8; ++t) {
    floatx4 acc = (floatx4){0.f, 0.f, 0.f, 0.f};
    for (int s = 0; s < 4; ++s)
      acc = __builtin_amdgcn_mfma_f32_16x16x32_bf16(niF[s], WF1[(s * 8 + t) * 64 + l], acc, 0, 0, 0);
    for (int s = 0; s < 4; ++s)
      acc = __builtin_amdgcn_mfma_f32_16x16x32_bf16(njF[s], WF2[(s * 8 + t) * 64 + l], acc, 0, 0, 0);
    for (int s = 0; s < 3; ++s)
      acc = __builtin_amdgcn_mfma_f32_16x16x32_bf16(eaF[s], WF4[(s * 8 + t) * 64 + l], acc, 0, 0, 0);
    float bias = bfv[lo + 16 * t];
    for (int i = 0; i < 4; ++i) {
      float v = acc[i] + bias;
      v = v > 0.f ? v : expm1f(v);
      v *= maskv[i];
      f_lds[w][quad * 4 + i][lo + 16 * t] = f2bf(v);
    }
  }
  for (int i = 0; i < 4; ++i) {
    const short8 fv = *(const short8*)&f_lds[w][quad * 4 + i][lo * 8];
    const short8 mv = *(const short8*)(M + (size_t)srcRow[i] * C + lo * 8);
    float d = 0.f;
    for (int j = 0; j < 8; ++j)
      d += bf2f((unsigned short)fv[j]) * bf2f((unsigned short)mv[j]);
    d += __shfl_xor(d, 1);
    d += __shfl_xor(d, 2);
    d += __shfl_xor(d, 4);
    d += __shfl_xor(d, 8);
    float a = tanhf(d);
    float cf = expf(a);
    if (lo == 0) atomicAdd(a_sum + srcRow[i], a);
    float* Prow = P + (size_t)srcRow[i] * C;
    for (int j = 0; j < 8; ++j)
      atomicAdd(Prow + lo * 8 + j, cf * bf2f((unsigned short)fv[j]));
  }
}

__global__ __launch_bounds__(256) void fb_node_kernel(
    const float* __restrict__ x, const float* __restrict__ P,
    const float* __restrict__ a_sum, const float* __restrict__ Wu,
    const float* __restrict__ bu, float* __restrict__ out) {
  __shared__ float rows[32][129];
  int b0 = blockIdx.x * 32;
  for (int idx = threadIdx.x; idx < 32 * 128; idx += 256) {
    int r = idx >> 7, i = idx & 127;
    int n = b0 + r;
    float v = 0.f;
    if (n < NN) v = x[(size_t)n * C + i] + expf(-a_sum[n]) * P[(size_t)n * C + i];
    rows[r][i] = v;
  }
  __syncthreads();
  int tr = threadIdx.x >> 4;
  int tc = threadIdx.x & 15;
  floatx4 a00 = (floatx4){0,0,0,0}, a01 = a00, a10 = a00, a11 = a00;
  for (int i = 0; i < C; ++i) {
    float r0 = rows[tr * 2][i], r1 = rows[tr * 2 + 1][i];
    const floatx4* wr = (const floatx4*)(Wu + (size_t)i * C + tc * 8);
    floatx4 w0 = wr[0], w1 = wr[1];
    a00 += w0 * r0; a01 += w1 * r0;
    a10 += w0 * r1; a11 += w1 * r1;
  }
  const floatx4* bv = (const floatx4*)(bu + tc * 8);
  floatx4 bb0 = bv[0], bb1 = bv[1];
  int n0 = b0 + tr * 2;
  if (n0 < NN) {
    floatx4* o = (floatx4*)(out + (size_t)n0 * C + tc * 8);
    o[0] = a00 + bb0; o[1] = a01 + bb1;
  }
  if (n0 + 1 < NN) {
    floatx4* o = (floatx4*)(out + (size_t)(n0 + 1) * C + tc * 8);
    o[0] = a10 + bb0; o[1] = a11 + bb1;
  }
}

extern "C" void kernel_launch(void* const* d_in, const int* in_sizes, int n_in,
                              void* d_out, int out_size, void* d_ws, size_t ws_size,
                              hipStream_t stream) {
  const float* x  = (const float*)d_in[0];
  const int*   ei = (const int*)d_in[1];
  const float* ea = (const float*)d_in[2];
  const float* Wf = (const float*)d_in[3];
  const float* bf = (const float*)d_in[4];
  const float* Wq = (const float*)d_in[5];
  const float* Wk = (const float*)d_in[6];
  const float* Wa = (const float*)d_in[7];
  const float* Wu = (const float*)d_in[8];
  const float* bu = (const float*)d_in[9];
  float* out = (float*)d_out;
  const int* src = ei;
  const int* tgt = ei + E_EDGES;

  size_t off = 0;
  auto take = [&](size_t n) { size_t r = off; off += (n + 255) & ~(size_t)255; return r; };
  size_t oZ    = take((size_t)E_EDGES * C * 2);   // 204.8 MB
  size_t oDeg  = take((size_t)NN * 4);
  size_t oCur  = take((size_t)NN * 4);            // adjacent to deg: one memset
  size_t oOffs = take((size_t)NN * 4);
  size_t oPerm = take((size_t)E_EDGES * 4);
  size_t oSrcs = take((size_t)E_EDGES * 4);
  size_t oTgts = take((size_t)E_EDGES * 4);
  size_t oWfr  = take((size_t)45056 * 2);
  size_t oWm   = take((size_t)C * C * 4);
  size_t oM    = take((size_t)NN * C * 2);
  size_t oXB   = take((size_t)NN * C * 2);
  size_t oA    = take((size_t)E_EDGES * 4);
  size_t need = off;

  if (ws_size >= need) {
    unsigned short* Z = (unsigned short*)((char*)d_ws + oZ);
    int* deg = (int*)((char*)d_ws + oDeg);
    int* cursor = (int*)((char*)d_ws + oCur);
    int* offs = (int*)((char*)d_ws + oOffs);
    int* perm = (int*)((char*)d_ws + oPerm);
    int* srcs = (int*)((char*)d_ws + oSrcs);
    int* tgts = (int*)((char*)d_ws + oTgts);
    unsigned short* wfrag = (unsigned short*)((char*)d_ws + oWfr);
    float* Wm = (float*)((char*)d_ws + oWm);
    unsigned short* M = (unsigned short*)((char*)d_ws + oM);
    unsigned short* XB = (unsigned short*)((char*)d_ws + oXB);
    float* A = (float*)((char*)d_ws + oA);

    hipMemsetAsync(deg, 0, oOffs - oDeg, stream);   // deg + cursor
    setup_kernel<<<3365, 256, 0, stream>>>(Wf, Wq, Wk, Wa, src, wfrag, Wm, deg);
    m_kernel<<<(NN + 31) / 32, 256, 0, stream>>>(x, Wm, M, XB);
    scan_kernel<<<1, 1024, 0, stream>>>(deg, offs);
    pos_kernel<<<E_EDGES / 256, 256, 0, stream>>>(src, tgt, offs, cursor, perm, srcs, tgts);
    edge_kernel<<<E_EDGES / 64, 256, 0, stream>>>(XB, ea, bf, wfrag, perm, srcs, tgts,
                                                  M, Z, A);
    gather_node_kernel<<<(NN + 31) / 32, 256, 0, stream>>>(x, Z, A, offs, deg, Wu, bu, out);
  } else {
    size_t f = 0;
    auto tk = [&](size_t n) { size_t r = f; f += (n + 255) & ~(size_t)255; return r; };
    size_t fP = tk((size_t)NN * C * 4);
    size_t fAs = tk((size_t)NN * 4);
    size_t fDeg = tk((size_t)NN * 4);
    size_t fWfr = tk((size_t)45056 * 2);
    size_t fWm = tk((size_t)C * C * 4);
    size_t fM = tk((size_t)NN * C * 2);
    float* P = (float*)((char*)d_ws + fP);
    float* a_sum = (float*)((char*)d_ws + fAs);
    int* deg = (int*)((char*)d_ws + fDeg);
    unsigned short* wfrag = (unsigned short*)((char*)d_ws + fWfr);
    float* Wm = (float*)((char*)d_ws + fWm);
    unsigned short* M = (unsigned short*)((char*)d_ws + fM);
    hipMemsetAsync(P, 0, (size_t)NN * C * 4 + 256 + NN * 4, stream);
    setup_kernel<<<3365, 256, 0, stream>>>(Wf, Wq, Wk, Wa, src, wfrag, Wm, deg);
    // Wm -> M via fused m_kernel (XB written into P scratch start is unsafe; reuse M only)
    m_kernel<<<(NN + 31) / 32, 256, 0, stream>>>(x, Wm, M, (unsigned short*)P);
    hipMemsetAsync(P, 0, (size_t)NN * C * 4, stream);  // re-zero P after XB scribble
    fb_edge_kernel<<<E_EDGES / 64, 256, 0, stream>>>(x, src, tgt, ea, bf, wfrag, M,
                                                     a_sum, P);
    fb_node_kernel<<<(NN + 31) / 32, 256, 0, stream>>>(x, P, a_sum, Wu, bu, out);
  }
}